// Round 3
// baseline (185.528 us; speedup 1.0000x reference)
//
#include <hip/hip_runtime.h>

typedef _Float16 half8 __attribute__((ext_vector_type(8)));
typedef float f32x16 __attribute__((ext_vector_type(16)));

#define WD 7
#define NPAD 128
#define KDIM 8330
#define KT 8448          // 8*KSLICE, multiple of 64; rows zero-padded past 8330
#define BSZ 4096
#define SPLITK 8
#define KSLICE 1056      // 33 * BK
#define NITER 33
#define BM 32
#define BK 32

// ws layout (bytes)
static constexpr size_t OFF_WT   = 0;                              // _Float16[2][128][KT]
static constexpr size_t WT_BYTES = (size_t)2 * NPAD * KT * 2;      // 4,325,376
static constexpr size_t OFF_BIAS = WT_BYTES;                       // 128 floats
static constexpr size_t OFF_PART = OFF_BIAS + 512;                 // [SPLITK][BSZ][NPAD] f32
// total: 4,325,888 + 16,777,216 = 21,103,104 B (budget proven >= 23.1 MB)

static __device__ const int KIDX[5][4] = {
    {0, 1, 3, 4}, {7, 8, 9, 10}, {5, 6, 11, 12}, {11, 12, 13, 14}, {15, 16, 15, 16}};
static __device__ const unsigned long long OBASE[5] = {0ull, 401408ull, 802816ull, 1204224ull, 1605632ull};

__device__ __forceinline__ unsigned pk16(_Float16 a, _Float16 b) {
  return (unsigned)__builtin_bit_cast(unsigned short, a) |
         ((unsigned)__builtin_bit_cast(unsigned short, b) << 16);
}

__device__ __forceinline__ void gload_lds16(const void* g, void* l) {
  __builtin_amdgcn_global_load_lds((const __attribute__((address_space(1))) unsigned int*)g,
                                   (__attribute__((address_space(3))) unsigned int*)l, 16, 0, 0);
}

// ---------------- pack: W -> transposed fp16 hi/lo wt[comp][n][k], bias
__global__ __launch_bounds__(256) void pack_kernel(
    const float* __restrict__ Wh, const float* __restrict__ bh,
    const float* __restrict__ Wa, const float* __restrict__ ba,
    const float* __restrict__ Wu, const float* __restrict__ bu,
    const float* __restrict__ Wl_, const float* __restrict__ bl,
    const float* __restrict__ Wf, const float* __restrict__ bf,
    char* __restrict__ wsb) {
  _Float16* wt_h = (_Float16*)(wsb + OFF_WT);
  _Float16* wt_l = wt_h + (size_t)NPAD * KT;
  float* bias = (float*)(wsb + OFF_BIAS);
  __shared__ _Float16 sh[64][128];
  __shared__ _Float16 sl[64][128];
  const int k0 = blockIdx.x * 64;
  const int tid = threadIdx.x;

#pragma unroll
  for (int jj = 0; jj < 32; ++jj) {
    int idx = tid + 256 * jj;
    int kk = idx >> 7, n = idx & 127;
    int k = k0 + kk;
    float w = 0.f;
    if (k < KDIM) {
      if      (n < 28)  w = Wh [k * 28 + n];
      else if (n < 56)  w = Wa [k * 28 + (n - 28)];
      else if (n < 84)  w = Wu [k * 28 + (n - 56)];
      else if (n < 112) w = Wl_[k * 28 + (n - 84)];
      else if (n < 126) w = Wf [k * 14 + (n - 112)];
    }
    _Float16 h = (_Float16)w;
    _Float16 l = (_Float16)((w - (float)h) * 2048.0f);
    sh[kk][n] = h;
    sl[kk][n] = l;
  }
  if (blockIdx.x == 0 && tid < NPAD) {
    int n = tid;
    float v = 0.f;
    if      (n < 28)  v = bh[n];
    else if (n < 56)  v = ba[n - 28];
    else if (n < 84)  v = bu[n - 56];
    else if (n < 112) v = bl[n - 84];
    else if (n < 126) v = bf[n - 112];
    bias[n] = v;
  }
  __syncthreads();
  const int n = tid >> 1;
  const int kc = (tid & 1) * 32;
  size_t ob = (size_t)n * KT + k0 + kc;
#pragma unroll
  for (int c = 0; c < 4; ++c) {
    uint4 qh, ql;
    qh.x = pk16(sh[kc + c * 8 + 0][n], sh[kc + c * 8 + 1][n]);
    qh.y = pk16(sh[kc + c * 8 + 2][n], sh[kc + c * 8 + 3][n]);
    qh.z = pk16(sh[kc + c * 8 + 4][n], sh[kc + c * 8 + 5][n]);
    qh.w = pk16(sh[kc + c * 8 + 6][n], sh[kc + c * 8 + 7][n]);
    ql.x = pk16(sl[kc + c * 8 + 0][n], sl[kc + c * 8 + 1][n]);
    ql.y = pk16(sl[kc + c * 8 + 2][n], sl[kc + c * 8 + 3][n]);
    ql.z = pk16(sl[kc + c * 8 + 4][n], sl[kc + c * 8 + 5][n]);
    ql.w = pk16(sl[kc + c * 8 + 6][n], sl[kc + c * 8 + 7][n]);
    *(uint4*)(wt_h + ob + c * 8) = qh;
    *(uint4*)(wt_l + ob + c * 8) = ql;
  }
}

// ---------------- GEMM: partial[s] = x[:, slice] @ W[slice, :]  (fp16x3, 32x32x16 MFMA)
__global__ __launch_bounds__(128, 2) void gemm_kernel(const float* __restrict__ x,
                                                      char* __restrict__ wsb) {
  const _Float16* wt = (const _Float16*)(wsb + OFF_WT);
  float* partial = (float*)(wsb + OFF_PART);
  const int row0 = blockIdx.x * BM;
  const int split = blockIdx.y;
  const int ks = split * KSLICE;

  // W: [buf][comp][kslot(4)][n(128)][8 halves]  (16 KB per buffer)
  __shared__ _Float16 wtile[2][2][4][128][8];
  // x: [comp][row(32)][40 halves]  (pad 8 -> 80 B rows, 16B-aligned)
  __shared__ _Float16 xtile[2][32][40];

  const int tid = threadIdx.x;
  const int lane = tid & 63;
  const int wid = tid >> 6;              // 0..1 : column half (64 cols)

  // x staging mapping: thread -> (row, 8 consecutive k)
  const int xrow = tid >> 2;             // 0..31
  const int xkc = (tid & 3) * 8;         // 0,8,16,24
  const float* xrp = x + (size_t)(row0 + xrow) * KDIM;

  // W staging: 16 chunks of 1KB, 8 per wave
  auto stageW = [&](int buf, int k0) {
#pragma unroll
    for (int c = 0; c < 8; ++c) {
      int i = wid * 8 + c;
      int comp = i >> 3, kslot = (i >> 1) & 3, nh = i & 1;
      const _Float16* src = wt + (size_t)comp * NPAD * KT +
                            (size_t)(nh * 64 + lane) * KT + k0 + kslot * 8;
      gload_lds16((const void*)src, (void*)&wtile[buf][comp][kslot][nh * 64][0]);
    }
  };

  float2 xv[4];
  auto loadX = [&](int k0g) {
    int kx = k0g + xkc;
    if (kx + 8 <= KDIM) {
#pragma unroll
      for (int j = 0; j < 4; ++j) xv[j] = *(const float2*)(xrp + kx + 2 * j);
    } else {
#pragma unroll
      for (int j = 0; j < 4; ++j) {
        xv[j].x = (kx + 2 * j     < KDIM) ? xrp[kx + 2 * j]     : 0.f;
        xv[j].y = (kx + 2 * j + 1 < KDIM) ? xrp[kx + 2 * j + 1] : 0.f;
      }
    }
  };
  auto writeX = [&]() {
    half8 hi, lo;
#pragma unroll
    for (int j = 0; j < 4; ++j) {
      float a = xv[j].x, b = xv[j].y;
      _Float16 ha = (_Float16)a, hb = (_Float16)b;
      hi[2 * j] = ha; hi[2 * j + 1] = hb;
      lo[2 * j]     = (_Float16)((a - (float)ha) * 2048.0f);
      lo[2 * j + 1] = (_Float16)((b - (float)hb) * 2048.0f);
    }
    *(half8*)&xtile[0][xrow][xkc] = hi;
    *(half8*)&xtile[1][xrow][xkc] = lo;
  };

  // prologue: stage tile 0
  stageW(0, ks);
  loadX(ks);
  asm volatile("s_waitcnt vmcnt(0)" ::: "memory");
  writeX();
  asm volatile("s_waitcnt lgkmcnt(0)\ns_barrier" ::: "memory");

  f32x16 accA[2], accB[2];
#pragma unroll
  for (int nt = 0; nt < 2; ++nt) {
    accA[nt] = (f32x16)(0.f);
    accB[nt] = (f32x16)(0.f);
  }

  const int arow = lane & 31;
  const int asub = lane >> 5;

  for (int t = 0; t < NITER; ++t) {
    const int cur = t & 1;
    const bool hasNext = (t + 1 < NITER);
    if (hasNext) loadX(ks + (t + 1) * BK);   // global -> regs, in flight across barriers

    half8 ah[2], al[2], bh[2][2], bl[2][2];
#pragma unroll
    for (int ksub = 0; ksub < 2; ++ksub) {
      ah[ksub] = *(const half8*)&xtile[0][arow][ksub * 16 + asub * 8];
      al[ksub] = *(const half8*)&xtile[1][arow][ksub * 16 + asub * 8];
    }
#pragma unroll
    for (int nt = 0; nt < 2; ++nt)
#pragma unroll
      for (int ksub = 0; ksub < 2; ++ksub) {
        int kslot = ksub * 2 + asub;
        int n = wid * 64 + nt * 32 + (lane & 31);
        bh[nt][ksub] = *(const half8*)&wtile[cur][0][kslot][n][0];
        bl[nt][ksub] = *(const half8*)&wtile[cur][1][kslot][n][0];
      }
    // all LDS reads of tile t done -> safe to overwrite buf^1 and xtile
    asm volatile("s_waitcnt lgkmcnt(0)\ns_barrier" ::: "memory");
    if (hasNext) stageW(cur ^ 1, ks + (t + 1) * BK);

#pragma unroll
    for (int nt = 0; nt < 2; ++nt)
#pragma unroll
      for (int ksub = 0; ksub < 2; ++ksub) {
        accA[nt] = __builtin_amdgcn_mfma_f32_32x32x16_f16(ah[ksub], bh[nt][ksub], accA[nt], 0, 0, 0);
        accB[nt] = __builtin_amdgcn_mfma_f32_32x32x16_f16(al[ksub], bh[nt][ksub], accB[nt], 0, 0, 0);
        accB[nt] = __builtin_amdgcn_mfma_f32_32x32x16_f16(ah[ksub], bl[nt][ksub], accB[nt], 0, 0, 0);
      }

    if (hasNext) {
      asm volatile("s_waitcnt vmcnt(0)" ::: "memory");  // x regs + W(t+1) LDS landed
      writeX();
    }
    asm volatile("s_waitcnt lgkmcnt(0)\ns_barrier" ::: "memory");
  }

  float* pb = partial + (size_t)split * BSZ * NPAD;
#pragma unroll
  for (int nt = 0; nt < 2; ++nt)
#pragma unroll
    for (int r = 0; r < 16; ++r) {
      int row = row0 + (r & 3) + 8 * (r >> 2) + 4 * asub;
      int col = wid * 64 + nt * 32 + (lane & 31);
      pb[(size_t)row * NPAD + col] = accA[nt][r] + accB[nt][r] * (1.0f / 2048.0f);
    }
}

// ---------------- fused reduce + epilogue
__device__ __forceinline__ void axis_mask(const float a[WD], int lo, int hi, float m[WD]) {
  float am[WD];
  float tot = 0.f;
#pragma unroll
  for (int c = 0; c < WD; ++c) { am[c] = (c >= lo) ? a[c] : 0.f; tot += am[c]; }
  float run = 0.f;
  float c1[WD];
#pragma unroll
  for (int c = 0; c < WD; ++c) {
    run += am[c] / tot;
    c1[c] = (run >= 0.3f) ? run : 0.f;
  }
  float tot2 = 0.f;
#pragma unroll
  for (int c = 0; c < WD; ++c) { am[c] = (c < hi) ? a[c] : 0.f; tot2 += am[c]; }
  run = 0.f;
#pragma unroll
  for (int c = 0; c < WD; ++c) {
    run += am[c] / tot2;
    float c2 = 1.f - run;
    c2 = (c2 >= 0.3f) ? c2 : 0.f;
    m[c] = c1[c] * c2;
  }
}

__global__ __launch_bounds__(256) void epi_kernel(const char* __restrict__ wsb,
                                                  const float* __restrict__ keypoint,
                                                  float* __restrict__ out) {
  int unit = blockIdx.x * 256 + threadIdx.x;
  if (unit >= BSZ * 5) return;
  int fam = unit >> 12;
  int b = unit & (BSZ - 1);
  const float* part = (const float*)(wsb + OFF_PART);
  const float* bias = (const float*)(wsb + OFF_BIAS);

  const int G = (fam == 4) ? 1 : 2;
  const int nk = (fam == 4) ? 2 : 4;
  const int base = fam * 28;
  const int ncol = (fam == 4) ? 14 : 28;

  // fused splitK reduction: same order as before (partials ascending, bias last)
  float vv[28];
#pragma unroll
  for (int c = 0; c < 28; ++c)
    vv[c] = (c < ncol) ? part[(size_t)b * NPAD + base + c] : 0.f;
#pragma unroll
  for (int sp = 1; sp < SPLITK; ++sp) {
    const float* pr = part + ((size_t)sp * BSZ + b) * NPAD + base;
#pragma unroll
    for (int c = 0; c < 28; ++c)
      if (c < ncol) vv[c] += pr[c];
  }
#pragma unroll
  for (int c = 0; c < 28; ++c)
    if (c < ncol) vv[c] += bias[base + c];

  int mnx = 7, mxx = -1, mny = 7, mxy = -1;
  for (int i = 0; i < nk; ++i) {
    int kidx = KIDX[fam][i];
    float fx = keypoint[((size_t)b * 17 + kidx) * 2 + 0];
    float fy = keypoint[((size_t)b * 17 + kidx) * 2 + 1];
    int ix = (int)floorf(fx * 7.0f); ix = ix < 6 ? ix : 6;
    int iy = (int)floorf(fy * 7.0f); iy = iy < 6 ? iy : 6;
    mnx = min(mnx, ix); mxx = max(mxx, ix);
    mny = min(mny, iy); mxy = max(mxy, iy);
  }
  int lox = mnx - 1; if (lox < 0) lox = 0;
  int hix = mxx + 1; if (hix > 6) hix = 6;
  int loy = mny - 1; if (loy < 0) loy = 0;
  int hiy = mxy + 1; if (hiy > 6) hiy = 6;

  float xmg[2][WD], ymg[2][WD];
  float mx = 0.f;
#pragma unroll
  for (int g = 0; g < 2; ++g) {
    if (g < G) {
      const float* vg = vv + g * 14;
      float a0[WD], a1[WD];
#pragma unroll
      for (int c = 0; c < WD; ++c) {
        float s0 = vg[c], s1 = vg[c + 7];
        float mM = fmaxf(s0, s1);
        float e0 = expf(s0 - mM), e1 = expf(s1 - mM);
        float sum = e0 + e1;
        a0[c] = expf(e0 / sum);
        a1[c] = expf(e1 / sum);
      }
      axis_mask(a0, lox, hix, xmg[g]);
      axis_mask(a1, loy, hiy, ymg[g]);
      float mx_x = 0.f, mx_y = 0.f;
#pragma unroll
      for (int c = 0; c < WD; ++c) {
        mx_x = fmaxf(mx_x, xmg[g][c]);
        mx_y = fmaxf(mx_y, ymg[g][c]);
      }
      mx = fmaxf(mx, mx_y * mx_x);
    }
  }

  float d = mx + 1e-7f;
  float* op = out + OBASE[fam] + (size_t)b * (G * 49);
#pragma unroll
  for (int g = 0; g < 2; ++g) {
    if (g < G) {
#pragma unroll
      for (int y = 0; y < WD; ++y) {
        float yv = ymg[g][y];
#pragma unroll
        for (int xx = 0; xx < WD; ++xx) {
          op[g * 49 + y * 7 + xx] = (yv * xmg[g][xx]) / d;
        }
      }
    }
  }
}

extern "C" void kernel_launch(void* const* d_in, const int* in_sizes, int n_in,
                              void* d_out, int out_size, void* d_ws, size_t ws_size,
                              hipStream_t stream) {
  const float* x        = (const float*)d_in[0];
  const float* keypoint = (const float*)d_in[1];
  const float* Wh = (const float*)d_in[2];
  const float* bh = (const float*)d_in[3];
  const float* Wa = (const float*)d_in[4];
  const float* ba = (const float*)d_in[5];
  const float* Wu = (const float*)d_in[6];
  const float* bu = (const float*)d_in[7];
  const float* Wl = (const float*)d_in[8];
  const float* bl = (const float*)d_in[9];
  const float* Wf = (const float*)d_in[10];
  const float* bf = (const float*)d_in[11];
  float* out = (float*)d_out;
  char* wsb  = (char*)d_ws;

  hipLaunchKernelGGL(pack_kernel, dim3(KT / 64), dim3(256), 0, stream,
                     Wh, bh, Wa, ba, Wu, bu, Wl, bl, Wf, bf, wsb);
  hipLaunchKernelGGL(gemm_kernel, dim3(BSZ / BM, SPLITK), dim3(128), 0, stream, x, wsb);
  hipLaunchKernelGGL(epi_kernel, dim3(BSZ * 5 / 256), dim3(256), 0, stream,
                     wsb, keypoint, out);
}

// Round 4
// 134.341 us; speedup vs baseline: 1.3810x; 1.3810x over previous
//
#include <hip/hip_runtime.h>

typedef _Float16 half8 __attribute__((ext_vector_type(8)));
typedef float f32x16 __attribute__((ext_vector_type(16)));

#define WD 7
#define NPAD 128
#define KDIM 8330
#define KT 8704          // 8 * KSLICE; wt rows zero-padded past 8330
#define BSZ 4096
#define SPLITK 8
#define KSLICE 1088      // 17 * 64
#define BM 64
#define BK 64
#define XROWB 272        // 256B row + 16B pad -> 4-way-max LDS bank conflicts

// ws layout (bytes)
static constexpr size_t OFF_WT   = 0;                              // _Float16[2][128][KT]
static constexpr size_t WT_BYTES = (size_t)2 * NPAD * KT * 2;      // 4,456,448
static constexpr size_t OFF_BIAS = WT_BYTES;                       // 128 floats
static constexpr size_t OFF_PART = OFF_BIAS + 512;                 // [SPLITK][BSZ][NPAD] f32
// total ~21.2 MB

static __device__ const int KIDX[5][4] = {
    {0, 1, 3, 4}, {7, 8, 9, 10}, {5, 6, 11, 12}, {11, 12, 13, 14}, {15, 16, 15, 16}};
static __device__ const unsigned long long OBASE[5] = {0ull, 401408ull, 802816ull, 1204224ull, 1605632ull};

__device__ __forceinline__ unsigned pk16(_Float16 a, _Float16 b) {
  return (unsigned)__builtin_bit_cast(unsigned short, a) |
         ((unsigned)__builtin_bit_cast(unsigned short, b) << 16);
}

__device__ __forceinline__ void gload_lds4(const void* g, void* l) {
  __builtin_amdgcn_global_load_lds((const __attribute__((address_space(1))) unsigned int*)g,
                                   (__attribute__((address_space(3))) unsigned int*)l, 4, 0, 0);
}

// ---------------- pack: W -> transposed fp16 hi/lo wt[comp][n][k], bias
__global__ __launch_bounds__(256) void pack_kernel(
    const float* __restrict__ Wh, const float* __restrict__ bh,
    const float* __restrict__ Wa, const float* __restrict__ ba,
    const float* __restrict__ Wu, const float* __restrict__ bu,
    const float* __restrict__ Wl_, const float* __restrict__ bl,
    const float* __restrict__ Wf, const float* __restrict__ bf,
    char* __restrict__ wsb) {
  _Float16* wt_h = (_Float16*)(wsb + OFF_WT);
  _Float16* wt_l = wt_h + (size_t)NPAD * KT;
  float* bias = (float*)(wsb + OFF_BIAS);
  __shared__ _Float16 sh[64][128];
  __shared__ _Float16 sl[64][128];
  const int k0 = blockIdx.x * 64;
  const int tid = threadIdx.x;

#pragma unroll
  for (int jj = 0; jj < 32; ++jj) {
    int idx = tid + 256 * jj;
    int kk = idx >> 7, n = idx & 127;
    int k = k0 + kk;
    float w = 0.f;
    if (k < KDIM) {
      if      (n < 28)  w = Wh [k * 28 + n];
      else if (n < 56)  w = Wa [k * 28 + (n - 28)];
      else if (n < 84)  w = Wu [k * 28 + (n - 56)];
      else if (n < 112) w = Wl_[k * 28 + (n - 84)];
      else if (n < 126) w = Wf [k * 14 + (n - 112)];
    }
    _Float16 h = (_Float16)w;
    _Float16 l = (_Float16)((w - (float)h) * 2048.0f);
    sh[kk][n] = h;
    sl[kk][n] = l;
  }
  if (blockIdx.x == 0 && tid < NPAD) {
    int n = tid;
    float v = 0.f;
    if      (n < 28)  v = bh[n];
    else if (n < 56)  v = ba[n - 28];
    else if (n < 84)  v = bu[n - 56];
    else if (n < 112) v = bl[n - 84];
    else if (n < 126) v = bf[n - 112];
    bias[n] = v;
  }
  __syncthreads();
  const int n = tid >> 1;
  const int kc = (tid & 1) * 32;
  size_t ob = (size_t)n * KT + k0 + kc;
#pragma unroll
  for (int c = 0; c < 4; ++c) {
    uint4 qh, ql;
    qh.x = pk16(sh[kc + c * 8 + 0][n], sh[kc + c * 8 + 1][n]);
    qh.y = pk16(sh[kc + c * 8 + 2][n], sh[kc + c * 8 + 3][n]);
    qh.z = pk16(sh[kc + c * 8 + 4][n], sh[kc + c * 8 + 5][n]);
    qh.w = pk16(sh[kc + c * 8 + 6][n], sh[kc + c * 8 + 7][n]);
    ql.x = pk16(sl[kc + c * 8 + 0][n], sl[kc + c * 8 + 1][n]);
    ql.y = pk16(sl[kc + c * 8 + 2][n], sl[kc + c * 8 + 3][n]);
    ql.z = pk16(sl[kc + c * 8 + 4][n], sl[kc + c * 8 + 5][n]);
    ql.w = pk16(sl[kc + c * 8 + 6][n], sl[kc + c * 8 + 7][n]);
    *(uint4*)(wt_h + ob + c * 8) = qh;
    *(uint4*)(wt_l + ob + c * 8) = ql;
  }
}

// ---------------- GEMM: partial[s] = x[:, slice] @ W[slice, :]
// x: global -> LDS via global_load_lds (fp32, counted vmcnt, double buffer)
// W: B fragments read directly from global (L2-resident per XCD)
__global__ __launch_bounds__(256, 2) void gemm_kernel(const float* __restrict__ x,
                                                      char* __restrict__ wsb) {
  const _Float16* wt = (const _Float16*)(wsb + OFF_WT);
  float* partial = (float*)(wsb + OFF_PART);
  const int bid = blockIdx.x;
  const int split = bid & 7;                 // consecutive bids -> different splits ->
  const int row0 = (bid >> 3) * BM;          // hw XCD round-robin pins split to one XCD
  const int ks = split * KSLICE;
  const int niter = (split == 7) ? 12 : 17;  // split 7 real K = 714 -> 12 tiles

  __shared__ char xlds[2][64 * XROWB];       // 34,816 B

  const int tid = threadIdx.x;
  const int lane = tid & 63;
  const int wid = tid >> 6;
  const int wm = wid & 1;                    // row half (32)
  const int wn = wid >> 1;                   // col half (64)

  // ---- x staging: wave w stages rows [w*16, w*16+16), one 256B row per call
  auto stageX = [&](int buf, int k0) {
    if (k0 + BK <= KDIM) {
#pragma unroll
      for (int r = 0; r < 16; ++r) {
        int row = wid * 16 + r;
        const float* src = x + (size_t)(row0 + row) * KDIM + k0 + lane;
        gload_lds4((const void*)src, (void*)(&xlds[buf][0] + row * XROWB));
      }
    } else {
#pragma unroll
      for (int r = 0; r < 16; ++r) {
        int row = wid * 16 + r;
        int k = k0 + lane;
        float v = (k < KDIM) ? x[(size_t)(row0 + row) * KDIM + k] : 0.f;
        *(float*)(&xlds[buf][row * XROWB + lane * 4]) = v;
      }
    }
  };

  // ---- B fragment base pointers: [comp][nt], 16B-aligned
  const _Float16* bp[2][2];
#pragma unroll
  for (int comp = 0; comp < 2; ++comp)
#pragma unroll
    for (int nt = 0; nt < 2; ++nt)
      bp[comp][nt] = wt + (size_t)comp * NPAD * KT +
                     (size_t)(wn * 64 + nt * 32 + (lane & 31)) * KT +
                     ks + (lane >> 5) * 8;

  f32x16 accA[2], accB[2];
#pragma unroll
  for (int nt = 0; nt < 2; ++nt) { accA[nt] = (f32x16)(0.f); accB[nt] = (f32x16)(0.f); }

  const int arow = lane & 31;
  const int ahalf = lane >> 5;

  // prologue: stage tile 0
  stageX(0, ks);
  asm volatile("s_waitcnt vmcnt(0) lgkmcnt(0)\ns_barrier" ::: "memory");

  for (int t = 0; t < niter; ++t) {
    const int cur = t & 1;
    if (t + 1 < niter) stageX(cur ^ 1, ks + (t + 1) * BK);  // stays in flight all iter

    // B fragments (global, L2): 16 x dwordx4
    half8 bh[2][4], bl[2][4];
#pragma unroll
    for (int nt = 0; nt < 2; ++nt)
#pragma unroll
      for (int ksub = 0; ksub < 4; ++ksub) {
        bh[nt][ksub] = *(const half8*)(bp[0][nt] + (size_t)t * BK + ksub * 16);
        bl[nt][ksub] = *(const half8*)(bp[1][nt] + (size_t)t * BK + ksub * 16);
      }

    // A fragments: LDS fp32 -> hi/lo fp16
    half8 ah[4], al[4];
    {
      const char* base = &xlds[cur][0] + (wm * 32 + arow) * XROWB + ahalf * 32;
#pragma unroll
      for (int ksub = 0; ksub < 4; ++ksub) {
        float4 f0 = *(const float4*)(base + ksub * 64);
        float4 f1 = *(const float4*)(base + ksub * 64 + 16);
        float f[8] = {f0.x, f0.y, f0.z, f0.w, f1.x, f1.y, f1.z, f1.w};
#pragma unroll
        for (int i = 0; i < 8; ++i) {
          _Float16 h = (_Float16)f[i];
          ah[ksub][i] = h;
          al[ksub][i] = (_Float16)((f[i] - (float)h) * 2048.0f);
        }
      }
    }

#pragma unroll
    for (int nt = 0; nt < 2; ++nt)
#pragma unroll
      for (int ksub = 0; ksub < 4; ++ksub) {
        accA[nt] = __builtin_amdgcn_mfma_f32_32x32x16_f16(ah[ksub], bh[nt][ksub], accA[nt], 0, 0, 0);
        accB[nt] = __builtin_amdgcn_mfma_f32_32x32x16_f16(al[ksub], bh[nt][ksub], accB[nt], 0, 0, 0);
        accB[nt] = __builtin_amdgcn_mfma_f32_32x32x16_f16(ah[ksub], bl[nt][ksub], accB[nt], 0, 0, 0);
      }

    // drain x(t+1) DMA + any ds writes, then cross-wave barrier
    asm volatile("s_waitcnt vmcnt(0) lgkmcnt(0)\ns_barrier" ::: "memory");
  }

  float* pb = partial + (size_t)split * BSZ * NPAD;
#pragma unroll
  for (int nt = 0; nt < 2; ++nt)
#pragma unroll
    for (int r = 0; r < 16; ++r) {
      int row = row0 + wm * 32 + (r & 3) + 8 * (r >> 2) + 4 * ahalf;
      int col = wn * 64 + nt * 32 + (lane & 31);
      pb[(size_t)row * NPAD + col] = accA[nt][r] + accB[nt][r] * (1.0f / 2048.0f);
    }
}

// ---------------- fused reduce + epilogue
__device__ __forceinline__ void axis_mask(const float a[WD], int lo, int hi, float m[WD]) {
  float am[WD];
  float tot = 0.f;
#pragma unroll
  for (int c = 0; c < WD; ++c) { am[c] = (c >= lo) ? a[c] : 0.f; tot += am[c]; }
  float run = 0.f;
  float c1[WD];
#pragma unroll
  for (int c = 0; c < WD; ++c) {
    run += am[c] / tot;
    c1[c] = (run >= 0.3f) ? run : 0.f;
  }
  float tot2 = 0.f;
#pragma unroll
  for (int c = 0; c < WD; ++c) { am[c] = (c < hi) ? a[c] : 0.f; tot2 += am[c]; }
  run = 0.f;
#pragma unroll
  for (int c = 0; c < WD; ++c) {
    run += am[c] / tot2;
    float c2 = 1.f - run;
    c2 = (c2 >= 0.3f) ? c2 : 0.f;
    m[c] = c1[c] * c2;
  }
}

__global__ __launch_bounds__(256) void epi_kernel(const char* __restrict__ wsb,
                                                  const float* __restrict__ keypoint,
                                                  float* __restrict__ out) {
  int unit = blockIdx.x * 256 + threadIdx.x;
  if (unit >= BSZ * 5) return;
  int fam = unit >> 12;
  int b = unit & (BSZ - 1);
  const float* part = (const float*)(wsb + OFF_PART);
  const float* bias = (const float*)(wsb + OFF_BIAS);

  const int G = (fam == 4) ? 1 : 2;
  const int nk = (fam == 4) ? 2 : 4;
  const int base = fam * 28;
  const int ncol = (fam == 4) ? 14 : 28;

  float vv[28];
#pragma unroll
  for (int c = 0; c < 28; ++c)
    vv[c] = (c < ncol) ? part[(size_t)b * NPAD + base + c] : 0.f;
#pragma unroll
  for (int sp = 1; sp < SPLITK; ++sp) {
    const float* pr = part + ((size_t)sp * BSZ + b) * NPAD + base;
#pragma unroll
    for (int c = 0; c < 28; ++c)
      if (c < ncol) vv[c] += pr[c];
  }
#pragma unroll
  for (int c = 0; c < 28; ++c)
    if (c < ncol) vv[c] += bias[base + c];

  int mnx = 7, mxx = -1, mny = 7, mxy = -1;
  for (int i = 0; i < nk; ++i) {
    int kidx = KIDX[fam][i];
    float fx = keypoint[((size_t)b * 17 + kidx) * 2 + 0];
    float fy = keypoint[((size_t)b * 17 + kidx) * 2 + 1];
    int ix = (int)floorf(fx * 7.0f); ix = ix < 6 ? ix : 6;
    int iy = (int)floorf(fy * 7.0f); iy = iy < 6 ? iy : 6;
    mnx = min(mnx, ix); mxx = max(mxx, ix);
    mny = min(mny, iy); mxy = max(mxy, iy);
  }
  int lox = mnx - 1; if (lox < 0) lox = 0;
  int hix = mxx + 1; if (hix > 6) hix = 6;
  int loy = mny - 1; if (loy < 0) loy = 0;
  int hiy = mxy + 1; if (hiy > 6) hiy = 6;

  float xmg[2][WD], ymg[2][WD];
  float mx = 0.f;
#pragma unroll
  for (int g = 0; g < 2; ++g) {
    if (g < G) {
      const float* vg = vv + g * 14;
      float a0[WD], a1[WD];
#pragma unroll
      for (int c = 0; c < WD; ++c) {
        float s0 = vg[c], s1 = vg[c + 7];
        float mM = fmaxf(s0, s1);
        float e0 = expf(s0 - mM), e1 = expf(s1 - mM);
        float sum = e0 + e1;
        a0[c] = expf(e0 / sum);
        a1[c] = expf(e1 / sum);
      }
      axis_mask(a0, lox, hix, xmg[g]);
      axis_mask(a1, loy, hiy, ymg[g]);
      float mx_x = 0.f, mx_y = 0.f;
#pragma unroll
      for (int c = 0; c < WD; ++c) {
        mx_x = fmaxf(mx_x, xmg[g][c]);
        mx_y = fmaxf(mx_y, ymg[g][c]);
      }
      mx = fmaxf(mx, mx_y * mx_x);
    }
  }

  float d = mx + 1e-7f;
  float* op = out + OBASE[fam] + (size_t)b * (G * 49);
#pragma unroll
  for (int g = 0; g < 2; ++g) {
    if (g < G) {
#pragma unroll
      for (int y = 0; y < WD; ++y) {
        float yv = ymg[g][y];
#pragma unroll
        for (int xx = 0; xx < WD; ++xx) {
          op[g * 49 + y * 7 + xx] = (yv * xmg[g][xx]) / d;
        }
      }
    }
  }
}

extern "C" void kernel_launch(void* const* d_in, const int* in_sizes, int n_in,
                              void* d_out, int out_size, void* d_ws, size_t ws_size,
                              hipStream_t stream) {
  const float* x        = (const float*)d_in[0];
  const float* keypoint = (const float*)d_in[1];
  const float* Wh = (const float*)d_in[2];
  const float* bh = (const float*)d_in[3];
  const float* Wa = (const float*)d_in[4];
  const float* ba = (const float*)d_in[5];
  const float* Wu = (const float*)d_in[6];
  const float* bu = (const float*)d_in[7];
  const float* Wl = (const float*)d_in[8];
  const float* bl = (const float*)d_in[9];
  const float* Wf = (const float*)d_in[10];
  const float* bf = (const float*)d_in[11];
  float* out = (float*)d_out;
  char* wsb  = (char*)d_ws;

  hipLaunchKernelGGL(pack_kernel, dim3(KT / 64), dim3(256), 0, stream,
                     Wh, bh, Wa, ba, Wu, bu, Wl, bl, Wf, bf, wsb);
  hipLaunchKernelGGL(gemm_kernel, dim3((BSZ / BM) * SPLITK), dim3(256), 0, stream, x, wsb);
  hipLaunchKernelGGL(epi_kernel, dim3(BSZ * 5 / 256), dim3(256), 0, stream,
                     wsb, keypoint, out);
}